// Round 15
// baseline (141.174 us; speedup 1.0000x reference)
//
#include <hip/hip_runtime.h>
#include <hip/hip_bf16.h>

// B=8, T=4096, C=384, H=64 causal single-head attention. fp32 in/out.
//
// Round-27: attn K/V LDS de-duplication via DMA rounds (r26's pattern).
// r26 post-mortem: Wt-via-LDS broke qkv's 46us invariant (total 160->139);
// zero-register DMA staging is the register-free prefetch that walls #1/#2
// blocked. attn (sole top-5, 47us, 56% stall) is L1-BW bound: each group's
// 4 waves redundantly load the same 16KB K/V tile = 4.2MB/CU L1 traffic
// (~66k cy ~= the stall). Fix: per round j, stage the 4 groups' tiles
// (64KB) into LDS by DMA; rounds synchronized by block barriers; round
// j+1's DMA issued BEFORE round j's compute (latency hidden, convoy
// defused -- post-barrier stalls are short ds_reads). k_ws/vt_ws tiles are
// contiguous 8KB blobs -> DMA is an identity copy; fragment reads become
// linear lane*16B ds_read_b128 (conflict-free, no swizzle). LDS 128KB dbuf
// + 17KB merge = 145KB, 1 block/CU (unchanged). do_tile softmax/PV/mask
// byte-identical. qkv/wtrans frozen at r26.
// Gates: attn FETCH ~6.2MB, WRITE ~8.2MB, VGPR <= ~90, LDS ~148K.
//
//  k_frag layout: [blk64][st][c8=h/8][i=m][j=h%8], row m of st holds
//                 K row s = 32*(st>>1) + 8*(m>>2) + 4*(st&1) + (m&3)
//  vt_frag layout: [st=row/64][dt=d/16][sc=s%64/8][i=d%16][j=s%8]

typedef __bf16 bf16x8 __attribute__((ext_vector_type(8)));
typedef float  f32x4  __attribute__((ext_vector_type(4)));

#define BB   8
#define TT   4096
#define CC   384
#define HH   64
#define NROW (BB*TT)       // 32768
// C^-0.5 * log2(e): fold softmax scale + exp2 conversion into q at projection
#define QSCALE (0.05103103630798288f * 1.4426950408889634f)

#if __has_builtin(__builtin_amdgcn_exp2f)
#define EXP2(x) __builtin_amdgcn_exp2f(x)
#else
#define EXP2(x) exp2f(x)
#endif

__device__ __forceinline__ unsigned short f2bf(float f) {
    __bf16 h = (__bf16)f;
    return __builtin_bit_cast(unsigned short, h);
}

// ---------------------------------------------------------------- kernel 1
// Wt[mat][h][c] = bf16(W[mat][c][h]), via LDS tile (coalesced both sides).
__global__ __launch_bounds__(256) void wtrans_kernel(
        const float* __restrict__ Wk,
        const float* __restrict__ Wq,
        const float* __restrict__ Wv,
        unsigned short* __restrict__ Wt) {
    __shared__ __align__(16) unsigned short tile[64][72];
    const float* Wm = (blockIdx.y == 0) ? Wk : ((blockIdx.y == 1) ? Wq : Wv);
    unsigned short* Wtm = Wt + blockIdx.y * (HH * CC);
    const int c0 = blockIdx.x * 64;
#pragma unroll
    for (int i = 0; i < 16; ++i) {
        int id = threadIdx.x + i * 256;         // 0..4095
        int c = id >> 6, h = id & 63;
        tile[c][h] = f2bf(Wm[(c0 + c) * HH + h]);   // coalesced read
    }
    __syncthreads();
#pragma unroll
    for (int i = 0; i < 16; ++i) {
        int id = threadIdx.x + i * 256;
        int h = id >> 6, c = id & 63;
        Wtm[h * CC + c0 + c] = tile[c][h];      // coalesced write
    }
}

// ---------------------------------------------------------------- kernel 2
// QKV projection (frozen at r26): both operands staged by global_load_lds
// DMA per 64-col chunk (dbuf); inner loop pure LDS->MFMA.
__global__ __launch_bounds__(256, 1) void qkv_kernel(
        const float* __restrict__ x,
        const unsigned short* __restrict__ Wt,     // [3][64][384] bf16
        unsigned short* __restrict__ q_ws,         // [32768][64] row-major, pre-scaled
        unsigned short* __restrict__ k_ws,         // fragment layout (permuted)
        unsigned short* __restrict__ vt_ws) {      // fragment layout
    __shared__ __align__(16) float xs2[2][32][64];              // 16384 B
    __shared__ __align__(16) unsigned short wts[2][3][64][64];  // 49152 B
    __shared__ __align__(16) unsigned short vtile[64][40];      //  5120 B

    const int lane = threadIdx.x & 63;
    const int wv   = threadIdx.x >> 6;     // 0..3
    const int rt   = wv & 1;               // row-tile (16 rows)
    const int hh   = wv >> 1;              // h-half (2 nt)
    const int l15  = lane & 15;
    const int quad = lane >> 4;
    const int rb   = blockIdx.x * 32;
    const int ntb  = hh * 2;               // first of this wave's two nt

    // ---- DMA one 64-col x chunk into xs2[bb] (2 instrs/wave) ----
    auto stageX = [&](int kk, int bb) {
#pragma unroll
        for (int j = 0; j < 2; ++j) {
            const int r0 = wv * 8 + j * 4;                 // instr's first row
            const int r  = r0 + quad;                      // this lane's row
            const int ch = l15 ^ (r & 7);                  // swizzled src chunk
            const float* src = x + (long)(rb + r) * CC + kk * 64 + ch * 4;
            float* dst = &xs2[bb][r0][0];                  // linear: +lane*16B
            __builtin_amdgcn_global_load_lds(
                (const __attribute__((address_space(1))) unsigned int*)src,
                (__attribute__((address_space(3))) unsigned int*)dst,
                16, 0, 0);
        }
    };

    // ---- DMA one 64-col Wt chunk [3][64][64] into wts[bb] (6 instrs/wave) --
    auto stageW = [&](int kk, int bb) {
#pragma unroll
        for (int i = 0; i < 6; ++i) {
            const int j   = wv + 4 * i;                    // 0..23
            const int m   = j >> 3;                        // 0..2
            const int rg  = j & 7;                         // row-group
            const int h   = rg * 8 + (lane >> 3);          // this lane's row
            const int chs = (lane & 7) ^ (h & 7);          // swizzled src chunk
            const unsigned short* src =
                Wt + m * (HH * CC) + h * CC + kk * 64 + chs * 8;
            unsigned short* dst = &wts[bb][m][rg * 8][0];  // linear: +lane*16B
            __builtin_amdgcn_global_load_lds(
                (const __attribute__((address_space(1))) unsigned int*)src,
                (__attribute__((address_space(3))) unsigned int*)dst,
                16, 0, 0);
        }
    };

    f32x4 acc[3][2];
    const f32x4 zero = {0.f, 0.f, 0.f, 0.f};
#pragma unroll
    for (int m = 0; m < 3; ++m)
#pragma unroll
        for (int n = 0; n < 2; ++n) acc[m][n] = zero;

    const int rloc = rt * 16 + l15;        // A-frag row (local)
    const int rx7  = rloc & 7;
    const int hx7  = l15 & 7;              // Wt read swizzle (h&7 == l15&7)

    stageX(0, 0);
    stageW(0, 0);
    __asm volatile("s_waitcnt vmcnt(0)" ::: "memory");
    __syncthreads();

#pragma unroll
    for (int kk = 0; kk < 6; ++kk) {
        const int cur = kk & 1;
        if (kk < 5) { stageX(kk + 1, cur ^ 1); stageW(kk + 1, cur ^ 1); }
#pragma unroll
        for (int h01 = 0; h01 < 2; ++h01) {
            const int chb = 8 * h01 + 2 * quad;
            const f32x4 xa = *reinterpret_cast<const f32x4*>(
                &xs2[cur][rloc][((chb) ^ rx7) * 4]);
            const f32x4 xb = *reinterpret_cast<const f32x4*>(
                &xs2[cur][rloc][((chb + 1) ^ rx7) * 4]);
            bf16x8 a;
#pragma unroll
            for (int e = 0; e < 4; ++e) {
                a[e]     = (__bf16)xa[e];
                a[4 + e] = (__bf16)xb[e];
            }
#pragma unroll
            for (int m = 0; m < 3; ++m)
#pragma unroll
                for (int n = 0; n < 2; ++n) {
                    const int hN = (ntb + n) * 16 + l15;
                    const bf16x8 bfr = *reinterpret_cast<const bf16x8*>(
                        &wts[cur][m][hN][(((h01 << 2) + quad) ^ hx7) << 3]);
                    acc[m][n] = __builtin_amdgcn_mfma_f32_16x16x32_bf16(
                        a, bfr, acc[m][n], 0, 0, 0);
                }
        }
        __asm volatile("s_waitcnt vmcnt(0)" ::: "memory");
        __syncthreads();
    }

    // Epilogue. C-layout: acc[m][n][r] = out[local row quad*4+r][h=(ntb+n)*16+l15]
#pragma unroll
    for (int n = 0; n < 2; ++n) {
        const int nt = ntb + n;
        const int h  = nt * 16 + l15;
        const int c8 = h >> 3;
        const int jj = h & 7;
#pragma unroll
        for (int r = 0; r < 4; ++r) {
            const int gr = rb + rt * 16 + quad * 4 + r;
            // k: permuted fragment position for local row s = gr & 63
            const int s   = gr & 63;
            const int stp = ((s >> 4) & 2) + ((s >> 2) & 1); // 2*(s>>5)+bit2
            const int ip  = ((s >> 1) & 12) + (s & 3);       // 4*((s>>3)&3)+(s&3)
            k_ws[(long)(gr >> 6) * 4096 + stp * 1024 + c8 * 128 + ip * 8 + jj]
                = f2bf(acc[0][n][r]);
            q_ws[gr * HH + h] = f2bf(acc[1][n][r] * QSCALE);
            vtile[h][rt * 16 + quad * 4 + r] = f2bf(acc[2][n][r]);
        }
    }
    __syncthreads();
    // vt fragment store: block covers sc-half (rb&32)>>3 of its 64-blk.
    {
        const int id  = threadIdx.x;               // 0..255
        const int dt  = id >> 6, scl = (id >> 4) & 3, ii = id & 15;
        const int sc  = scl + ((rb >> 3) & 4);
        unsigned short* dst = vt_ws + (long)(rb >> 6) * 4096
                              + (dt * 8 + sc) * 128 + ii * 8;
        *reinterpret_cast<uint4*>(dst) =
            *reinterpret_cast<const uint4*>(&vtile[dt * 16 + ii][scl * 8]);
    }
}

// ---------------------------------------------------------------- kernel 3
// Flash attention. 256 blocks x 1024 thr; block (p,b) does q-tile A=63-p
// then B=p. 16 waves = 4 groups x 4 waves; round j: group g computes tile
// t=4j+g from LDS. K/V tiles (contiguous 8KB blobs in k_ws/vt_ws) are DMA'd
// identity-copy into kvbuf[2][4][16KB]; round j+1's DMA issues before round
// j's compute (latency hidden under ~1000cy of MFMA/softmax). Fragment
// reads are linear lane*16B ds_read_b128 (conflict-free). Softmax
// (defer-max THR=8, per-quad lsum) and merge unchanged from r25.
__global__ __launch_bounds__(1024, 4) void attn_kernel(
        const unsigned short* __restrict__ q_ws,
        const unsigned short* __restrict__ k_ws,   // permuted fragment layout
        const unsigned short* __restrict__ vt_ws,  // fragment layout
        float* __restrict__ out) {
    __shared__ __align__(16) unsigned short kvbuf[2][4][8192];   // 131072 B
    __shared__ __align__(16) float xchg[64 * 65];                //  16640 B
    __shared__ float mx1[64], lx1[64];

    const int lane = threadIdx.x & 63;
    const int wv16 = threadIdx.x >> 6;     // 0..15
    const int grp  = wv16 >> 2;            // wave-group 0..3
    const int wg   = wv16 & 3;             // wave within group
    const int l15  = lane & 15;
    const int quad = lane >> 4;

    const int bid = blockIdx.x;
    const int b   = bid & 7;               // batch <-> XCD affinity
    const int p   = bid >> 3;              // 0..31

    const f32x4 zero = {0.f, 0.f, 0.f, 0.f};

    // -------- DMA round j's 4 tiles into kvbuf[bb] (4 instrs/wave) --------
    // wave w stages 4KB slice (w&3) of tile 4j+(w>>2): qq 0-1 = K halves,
    // qq 2-3 = V halves; identity copy (src and dst both linear).
    auto stage_round = [&](int j, int bb, int qt) {
        const int tg = 4 * j + grp;            // tile this wave stages
        if (tg > qt) return;
        const int qq = wg;
        const char* srcb;
        int dstoff;
        if (qq < 2) {
            srcb = (const char*)(k_ws + ((long)((b * TT + tg * 64) >> 4)) * 1024)
                   + qq * 4096;
            dstoff = qq * 4096;
        } else {
            srcb = (const char*)(vt_ws + ((long)((b * TT + tg * 64) >> 6)) * 4096)
                   + (qq - 2) * 4096;
            dstoff = 8192 + (qq - 2) * 4096;
        }
        char* dstb = (char*)&kvbuf[bb][grp][0] + dstoff;
#pragma unroll
        for (int i = 0; i < 4; ++i) {
            __builtin_amdgcn_global_load_lds(
                (const __attribute__((address_space(1))) unsigned int*)
                    (srcb + i * 1024 + lane * 16),
                (__attribute__((address_space(3))) unsigned int*)(dstb + i * 1024),
                16, 0, 0);
        }
    };

    // -------- one k-tile (K/V from kvbuf[cur][grp]) --------
    auto do_tile = [&](int t, int qt, int qrow, int cur,
                       const bf16x8& qf0, const bf16x8& qf1,
                       f32x4* o, float& mprev, float& lsum) {
        const int s0 = t * 64;
        const unsigned short* kvt = &kvbuf[cur][grp][0];

        bf16x8 ka0[4], ka1[4];
#pragma unroll
        for (int st = 0; st < 4; ++st) {
            ka0[st] = *reinterpret_cast<const bf16x8*>(
                kvt + st * 1024 + lane * 8);
            ka1[st] = *reinterpret_cast<const bf16x8*>(
                kvt + st * 1024 + 512 + lane * 8);
        }
        bf16x8 vb0[4], vb1[4];
#pragma unroll
        for (int dt = 0; dt < 4; ++dt) {
            vb0[dt] = *reinterpret_cast<const bf16x8*>(
                kvt + 4096 + dt * 1024 + lane * 8);
            vb1[dt] = *reinterpret_cast<const bf16x8*>(
                kvt + 4096 + dt * 1024 + 512 + lane * 8);
        }

        f32x4 sc[4];
        __builtin_amdgcn_s_setprio(1);
#pragma unroll
        for (int st = 0; st < 4; ++st) {
            f32x4 z = zero;
            z = __builtin_amdgcn_mfma_f32_16x16x32_bf16(ka0[st], qf0, z, 0, 0, 0);
            z = __builtin_amdgcn_mfma_f32_16x16x32_bf16(ka1[st], qf1, z, 0, 0, 0);
            sc[st] = z;
        }
        __builtin_amdgcn_s_setprio(0);

        if (t == qt) {                    // causal mask, diagonal tile only
            // permuted row map: s_local = 32*(st>>1) + 8*quad + 4*(st&1) + r
#pragma unroll
            for (int st = 0; st < 4; ++st)
#pragma unroll
                for (int r = 0; r < 4; ++r) {
                    int sg = s0 + ((st >> 1) << 5) + (quad << 3)
                               + ((st & 1) << 2) + r;
                    if (sg > qrow) sc[st][r] = -1e30f;
                }
        }

        float mloc = -1e30f;
#pragma unroll
        for (int st = 0; st < 4; ++st)
#pragma unroll
            for (int r = 0; r < 4; ++r) mloc = fmaxf(mloc, sc[st][r]);
        mloc = fmaxf(mloc, __shfl_xor(mloc, 16));
        mloc = fmaxf(mloc, __shfl_xor(mloc, 32));

        // defer-max: keep old max when the tile max is within THR=8
        // (exp2 domain; P bounded by 2^8=256, bf16/fp32-safe).
        if (!__all(mloc <= mprev + 8.0f)) {
            const float mnew = fmaxf(mprev, mloc);
            const float alpha = EXP2(mprev - mnew);
            lsum *= alpha;
            float ar[4];
#pragma unroll
            for (int r = 0; r < 4; ++r) ar[r] = __shfl(alpha, quad * 4 + r);
#pragma unroll
            for (int dt = 0; dt < 4; ++dt)
#pragma unroll
                for (int r = 0; r < 4; ++r) o[dt][r] *= ar[r];
            mprev = mnew;
        }

        // exp2 against (possibly stale) mprev; lsum stays per-quad partial.
        float psum = 0.f;
#pragma unroll
        for (int st = 0; st < 4; ++st)
#pragma unroll
            for (int r = 0; r < 4; ++r) {
                float pv = EXP2(sc[st][r] - mprev);
                psum += pv;
                sc[st][r] = pv;
            }
        lsum += psum;

        // P in-register: sc[st][r] already in PV A-fragment order.
        bf16x8 pf0, pf1;
#pragma unroll
        for (int r = 0; r < 4; ++r) {
            pf0[r]     = (__bf16)sc[0][r];
            pf0[4 + r] = (__bf16)sc[1][r];
            pf1[r]     = (__bf16)sc[2][r];
            pf1[4 + r] = (__bf16)sc[3][r];
        }
        __builtin_amdgcn_s_setprio(1);
#pragma unroll
        for (int dt = 0; dt < 4; ++dt) {
            o[dt] = __builtin_amdgcn_mfma_f32_16x16x32_bf16(pf0, vb0[dt], o[dt], 0, 0, 0);
            o[dt] = __builtin_amdgcn_mfma_f32_16x16x32_bf16(pf1, vb1[dt], o[dt], 0, 0, 0);
        }
        __builtin_amdgcn_s_setprio(0);
    };

    // -------- merge groups 1..3 into group 0, then store q-tile `qt` --------
    auto merge_store = [&](int qt, f32x4* o, float& mprev, float& lsum) {
        // complete the deferred quad-reduction of lsum (once per phase)
        lsum += __shfl_xor(lsum, 16);
        lsum += __shfl_xor(lsum, 32);
        for (int rr = 1; rr < 4; ++rr) {
            __syncthreads();
            if (grp == rr) {
                if (quad == 0) { mx1[wg * 16 + l15] = mprev; lx1[wg * 16 + l15] = lsum; }
#pragma unroll
                for (int dt = 0; dt < 4; ++dt)
#pragma unroll
                    for (int r = 0; r < 4; ++r)
                        xchg[(wg * 16 + quad * 4 + r) * 65 + dt * 16 + l15] = o[dt][r];
            }
            __syncthreads();
            if (grp == 0) {
#pragma unroll
                for (int r = 0; r < 4; ++r) {
                    const int row = wg * 16 + quad * 4 + r;
                    const float m0r = __shfl(mprev, quad * 4 + r);
                    const float m1r = mx1[row];
                    const float ms  = fmaxf(m0r, m1r);
                    const float w0  = EXP2(m0r - ms);
                    const float w1  = EXP2(m1r - ms);
#pragma unroll
                    for (int dt = 0; dt < 4; ++dt)
                        o[dt][r] = o[dt][r] * w0 + xchg[row * 65 + dt * 16 + l15] * w1;
                }
                const float m1l = mx1[wg * 16 + l15];
                const float msl = fmaxf(mprev, m1l);
                lsum = EXP2(mprev - msl) * lsum + EXP2(m1l - msl) * lx1[wg * 16 + l15];
                mprev = msl;
            }
        }
        if (grp == 0) {
            float rl[4];
#pragma unroll
            for (int r = 0; r < 4; ++r) rl[r] = 1.0f / __shfl(lsum, quad * 4 + r);
            const int orow = qt * 64 + wg * 16 + quad * 4;
#pragma unroll
            for (int dt = 0; dt < 4; ++dt)
#pragma unroll
                for (int r = 0; r < 4; ++r)
                    out[(long)(b * TT + orow + r) * HH + dt * 16 + l15] = o[dt][r] * rl[r];
        }
        __syncthreads();   // xchg/mx1/kvbuf reusable by next phase
    };

    // -------- one full phase for q-tile qt --------
    auto run_phase = [&](int qt) {
        const int qrow = qt * 64 + wg * 16 + l15;
        const unsigned short* qbase = q_ws + (b * TT + qrow) * HH;
        const bf16x8 qf0 = *reinterpret_cast<const bf16x8*>(qbase + quad * 8);
        const bf16x8 qf1 = *reinterpret_cast<const bf16x8*>(qbase + 32 + quad * 8);
        f32x4 o[4];
#pragma unroll
        for (int dt = 0; dt < 4; ++dt) o[dt] = zero;
        float mprev = -1e30f, lsum = 0.f;

        const int rounds = (qt >> 2) + 1;
        int cur = 0;
        stage_round(0, 0, qt);
        __asm volatile("s_waitcnt vmcnt(0)" ::: "memory");
        __syncthreads();
        for (int j = 0; j < rounds; ++j) {
            if (j + 1 < rounds) stage_round(j + 1, cur ^ 1, qt);
            __asm volatile("" ::: "memory");   // pin DMA issue before compute
            const int t = 4 * j + grp;
            if (t <= qt) do_tile(t, qt, qrow, cur, qf0, qf1, o, mprev, lsum);
            __asm volatile("s_waitcnt vmcnt(0)" ::: "memory");
            __syncthreads();
            cur ^= 1;
        }
        merge_store(qt, o, mprev, lsum);
    };

    run_phase(63 - p);     // phase A
    run_phase(p);          // phase B
}

// ---------------------------------------------------------------- launch
extern "C" void kernel_launch(void* const* d_in, const int* in_sizes, int n_in,
                              void* d_out, int out_size, void* d_ws, size_t ws_size,
                              hipStream_t stream) {
    const float* x  = (const float*)d_in[0];
    const float* Wk = (const float*)d_in[1];
    const float* Wq = (const float*)d_in[2];
    const float* Wv = (const float*)d_in[3];
    float* out = (float*)d_out;

    char* ws = (char*)d_ws;
    unsigned short* Wt    = (unsigned short*)(ws);                         // 147456 B
    unsigned short* q_ws  = (unsigned short*)(ws + 147456);                // 4 MiB
    unsigned short* k_ws  = (unsigned short*)(ws + 147456 + 4194304);      // 4 MiB
    unsigned short* vt_ws = (unsigned short*)(ws + 147456 + 2 * 4194304);  // 4 MiB

    wtrans_kernel<<<dim3(6, 3), 256, 0, stream>>>(Wk, Wq, Wv, Wt);
    qkv_kernel<<<NROW / 32, 256, 0, stream>>>(x, Wt, q_ws, k_ws, vt_ws);
    attn_kernel<<<(TT / 128) * BB, 1024, 0, stream>>>(q_ws, k_ws, vt_ws, out);
}